// Round 1
// baseline (314.605 us; speedup 1.0000x reference)
//
#include <hip/hip_runtime.h>

#define NC 32
#define NR 512

// ---------------------------------------------------------------------------
// Kernel 1: transpose the three [C=32, R=512] tables into [R=512, C=32] in ws
// so that all 32 components of one resolution row are contiguous (128 B line).
// ---------------------------------------------------------------------------
__global__ __launch_bounds__(256) void transpose_vecs(
    const float* __restrict__ vx, const float* __restrict__ vy,
    const float* __restrict__ vz, float* __restrict__ tx,
    float* __restrict__ ty, float* __restrict__ tz) {
  int u = blockIdx.x * 256 + threadIdx.x;           // 0 .. 3*16384-1
  if (u >= 3 * NC * NR) return;
  int table = u >> 14;                              // /16384
  int e = u & (NC * NR - 1);                        // c*512 + r
  int c = e >> 9;
  int r = e & (NR - 1);
  const float* src = (table == 0) ? vx : (table == 1) ? vy : vz;
  float* dst = (table == 0) ? tx : (table == 1) ? ty : tz;
  dst[r * NC + c] = src[e];
}

// ---------------------------------------------------------------------------
// 1D linear interp with grid_sample(align_corners=True, padding='zeros')
// semantics, returning 4 components at once from a transposed [R, C] table.
// Validity is folded into the weights (matches ref: invalid gather -> 0).
// ---------------------------------------------------------------------------
__device__ __forceinline__ float4 sample4_t(const float* __restrict__ t,
                                            float x, int c4) {
  float ix = (x + 1.0f) * 0.5f * (float)(NR - 1);
  float f = floorf(ix);
  float w = ix - f;
  int i0 = (int)f;
  int i1 = i0 + 1;
  float m0 = (i0 >= 0 && i0 < NR) ? (1.0f - w) : 0.0f;
  float m1 = (i1 >= 0 && i1 < NR) ? w : 0.0f;
  int ci0 = min(max(i0, 0), NR - 1);
  int ci1 = min(max(i1, 0), NR - 1);
  float4 v0 = *(const float4*)(t + ci0 * NC + c4);
  float4 v1 = *(const float4*)(t + ci1 * NC + c4);
  float4 r;
  r.x = v0.x * m0 + v1.x * m1;
  r.y = v0.y * m0 + v1.y * m1;
  r.z = v0.z * m0 + v1.z * m1;
  r.w = v0.w * m0 + v1.w * m1;
  return r;
}

// Fallback path: untransposed [C, R] tables (only used if ws_size too small).
__device__ __forceinline__ float4 sample4_u(const float* __restrict__ t,
                                            float x, int c4) {
  float ix = (x + 1.0f) * 0.5f * (float)(NR - 1);
  float f = floorf(ix);
  float w = ix - f;
  int i0 = (int)f;
  int i1 = i0 + 1;
  float m0 = (i0 >= 0 && i0 < NR) ? (1.0f - w) : 0.0f;
  float m1 = (i1 >= 0 && i1 < NR) ? w : 0.0f;
  int ci0 = min(max(i0, 0), NR - 1);
  int ci1 = min(max(i1, 0), NR - 1);
  float4 r;
  float* rp = (float*)&r;
  for (int j = 0; j < 4; ++j) {
    float v0 = t[(c4 + j) * NR + ci0];
    float v1 = t[(c4 + j) * NR + ci1];
    rp[j] = v0 * m0 + v1 * m1;
  }
  return r;
}

// ---------------------------------------------------------------------------
// Kernel 2: one thread = 4 components of one point. 8 lanes share a point.
// Stores are float4, fully coalesced (128 B per point, 1 KB per wave-store).
// Table loads are dwordx4, one 128 B line per (point, axis, neighbor).
// ---------------------------------------------------------------------------
template <bool TRANSPOSED>
__global__ __launch_bounds__(256) void cp_encode(
    const float* __restrict__ pos, const float* __restrict__ tx,
    const float* __restrict__ ty, const float* __restrict__ tz,
    float* __restrict__ out, int npts) {
  int t = blockIdx.x * 256 + threadIdx.x;
  int p = t >> 3;              // point index
  if (p >= npts) return;
  int c4 = (t & 7) * 4;        // first component of this thread's quad

  float x = pos[3 * p + 0];
  float y = pos[3 * p + 1];
  float z = pos[3 * p + 2];

  float4 fx, fy, fz;
  if (TRANSPOSED) {
    fx = sample4_t(tx, x, c4);
    fy = sample4_t(ty, y, c4);
    fz = sample4_t(tz, z, c4);
  } else {
    fx = sample4_u(tx, x, c4);
    fy = sample4_u(ty, y, c4);
    fz = sample4_u(tz, z, c4);
  }

  float4 r;
  r.x = fx.x * fy.x * fz.x;
  r.y = fx.y * fy.y * fz.y;
  r.z = fx.z * fy.z * fz.z;
  r.w = fx.w * fy.w * fz.w;
  *(float4*)(out + (long long)p * NC + c4) = r;
}

extern "C" void kernel_launch(void* const* d_in, const int* in_sizes, int n_in,
                              void* d_out, int out_size, void* d_ws,
                              size_t ws_size, hipStream_t stream) {
  const float* pos = (const float*)d_in[0];
  const float* vx = (const float*)d_in[1];
  const float* vy = (const float*)d_in[2];
  const float* vz = (const float*)d_in[3];
  float* out = (float*)d_out;
  int npts = in_sizes[0] / 3;

  const size_t tbytes = (size_t)3 * NC * NR * sizeof(float);  // 192 KiB
  int total_threads = npts * 8;
  int blocks = (total_threads + 255) / 256;

  if (ws_size >= tbytes) {
    float* tx = (float*)d_ws;
    float* ty = tx + NC * NR;
    float* tz = ty + NC * NR;
    int tb = (3 * NC * NR + 255) / 256;
    transpose_vecs<<<tb, 256, 0, stream>>>(vx, vy, vz, tx, ty, tz);
    cp_encode<true><<<blocks, 256, 0, stream>>>(pos, tx, ty, tz, out, npts);
  } else {
    cp_encode<false><<<blocks, 256, 0, stream>>>(pos, vx, vy, vz, out, npts);
  }
}